// Round 16
// baseline (285.588 us; speedup 1.0000x reference)
//
#include <hip/hip_runtime.h>
#include <hip/hip_fp16.h>

#define NN 20000      // nodes
#define NE 320000     // edges
#define FE 32         // edge feature dim
#define NG 64         // graphs
#define EA_STRIDE 36  // padded LDS row stride (floats)

using f16x8 = __attribute__((ext_vector_type(8))) _Float16;
using f32x4 = __attribute__((ext_vector_type(4))) float;

union AFrag {
    f16x8 v;
    __half2 h2[4];
};

struct Params {
    const float* x; const int* ei; const float* ea; const int* batch;
    const float* We; const float* be; const float* Wroot; const float* bconv;
    const float* Wgat; const float* a_src; const float* a_dst; const float* bgat;
    const float* Wfc1; const float* bfc1; const float* Wfc2; const float* bfc2;
    float* out;
    float* agg; float* gacc; float* den;
    __half* hpb; float* sc_s; float* sc_d;
};

static __device__ inline int lbound(const int* b, int key) {
    int lo = 0, hi = NN;
    while (lo < hi) { int mid = (lo + hi) >> 1; if (b[mid] < key) lo = mid + 1; else hi = mid; }
    return lo;
}

// ---------------- K1: NNConv msg; in-block we2t build; 4-tile waves, software pipeline ----------------
// K permutation: k in [0,512): ks=k>>5, r=k&31, q=r>>3, j=r&7; f=16*(q>>1)+ks; i=(q&1)*8+j
// k in [512,528): bias row i=k-512 ; k in [528,544): zero.
#define TPW 4
__global__ __launch_bounds__(256) void k_msg(Params p) {
    __shared__ __half swe[16 * 544];               // 17.0 KB: K-permuted f16 We2t
    __shared__ float lds[4][2][16 * EA_STRIDE];    // 18.4 KB: ea staging (dbuf per wave)
    const int tid  = threadIdx.x;
    const int lane = tid & 63;
    const int wid  = tid >> 6;
    const int m    = lane & 15;
    const int quad = lane >> 4;
    const int pp   = quad >> 1;
    const int xh   = (quad & 1) * 8;
    const int eL   = lane >> 3;
    const int fL   = (lane & 7) * 4;

    // build We2t in LDS (once per block, amortized over 4 waves x 4 tiles)
    for (int i = tid; i < 16 * 544; i += 256) {
        int k = i % 544, mm = i / 544;
        float v;
        if (k < 512) {
            int ks = k >> 5, r = k & 31, q = r >> 3, j = r & 7;
            int f = 16 * (q >> 1) + ks;
            int ii = (q & 1) * 8 + j;
            v = p.We[f * 256 + ii * 16 + mm];
        } else if (k < 528) v = p.be[(k - 512) * 16 + mm];
        else v = 0.f;
        swe[i] = __float2half(v);
    }
    __syncthreads();

    const int gw = blockIdx.x * 4 + wid;   // 1250 blocks x 4 waves
    const int t0 = gw * TPW;

    const __half* wt = swe + m * 544 + quad * 8;
    f16x8 bfr[17];
    #pragma unroll
    for (int ks = 0; ks < 17; ++ks)
        bfr[ks] = *(const f16x8*)(wt + ks * 32);

    // ---- prologue: tile0 scalars + ea + x ----
    int e0 = t0 * 16;
    int r  = e0 + quad * 4 + (m & 3);
    int s = p.ei[e0 + m];
    int d = p.ei[NE + r];
    {
        const float4* s0 = (const float4*)(p.ea + (long)t0 * 512 + lane * 4);
        float4 v0 = s0[0], v1 = s0[64];
        *(float4*)&lds[wid][0][eL * EA_STRIDE + fL]       = v0;
        *(float4*)&lds[wid][0][(8 + eL) * EA_STRIDE + fL] = v1;
    }
    float xf[8];
    {
        const float4* xr = (const float4*)(p.x + s * 16 + xh);
        float4 a0 = xr[0], a1 = xr[1];
        xf[0]=a0.x; xf[1]=a0.y; xf[2]=a0.z; xf[3]=a0.w;
        xf[4]=a1.x; xf[5]=a1.y; xf[6]=a1.z; xf[7]=a1.w;
    }

    int buf = 0;
    #pragma unroll
    for (int it = 0; it < TPW; ++it) {
        const int tile = t0 + it;
        const bool hasnext = it < TPW - 1;

        // prefetch next tile's independent loads (ea + scalars)
        float4 nv0, nv1;
        int s_n = 0, d_n = 0;
        if (hasnext) {
            const float4* sn = (const float4*)(p.ea + (long)(tile + 1) * 512 + lane * 4);
            nv0 = sn[0]; nv1 = sn[64];
            int e0n = (tile + 1) * 16;
            int rn  = e0n + quad * 4 + (m & 3);
            s_n = p.ei[e0n + m];
            d_n = p.ei[NE + rn];
        }

        // this tile's ea from LDS
        float4 ev[4];
        #pragma unroll
        for (int q = 0; q < 4; ++q)
            ev[q] = *(const float4*)&lds[wid][buf][m * EA_STRIDE + pp * 16 + q * 4];

        __half2 xp[4];
        #pragma unroll
        for (int j = 0; j < 4; ++j)
            xp[j] = __float22half2_rn(make_float2(xf[2*j], xf[2*j+1]));

        f32x4 acc = {0.f, 0.f, 0.f, 0.f};
        #pragma unroll
        for (int ks = 0; ks < 16; ++ks) {
            float evv = ((const float*)ev)[ks];
            __half2 eh = __float2half2_rn(evv);
            AFrag a;
            #pragma unroll
            for (int j = 0; j < 4; ++j) a.h2[j] = __hmul2(eh, xp[j]);
            acc = __builtin_amdgcn_mfma_f32_16x16x32_f16(a.v, bfr[ks], acc, 0, 0, 0);
        }
        {
            AFrag a;
            #pragma unroll
            for (int j = 0; j < 4; ++j) a.h2[j] = xp[j];
            acc = __builtin_amdgcn_mfma_f32_16x16x32_f16(a.v, bfr[16], acc, 0, 0, 0);
        }

        // dependent x gather for next tile — after compute, before atomics
        if (hasnext) {
            const float4* xr = (const float4*)(p.x + s_n * 16 + xh);
            float4 a0 = xr[0], a1 = xr[1];
            xf[0]=a0.x; xf[1]=a0.y; xf[2]=a0.z; xf[3]=a0.w;
            xf[4]=a1.x; xf[5]=a1.y; xf[6]=a1.z; xf[7]=a1.w;
        }

        #pragma unroll
        for (int rr = 0; rr < 4; ++rr) {
            int dd = __shfl(d, (quad << 4) | rr);
            atomicAdd(&p.agg[dd * 16 + m], acc[rr]);
        }

        if (hasnext) {
            buf ^= 1;
            *(float4*)&lds[wid][buf][eL * EA_STRIDE + fL]       = nv0;
            *(float4*)&lds[wid][buf][(8 + eL) * EA_STRIDE + fL] = nv1;
            s = s_n; d = d_n;
        }
    }
}

// ---------------- K2: node — h, hp, scores ----------------
__global__ __launch_bounds__(256) void k_node(Params p) {
    int n = (blockIdx.x * blockDim.x + threadIdx.x) >> 6;
    int lane = threadIdx.x & 63;
    if (n >= NN) return;
    int o = lane & 15;
    float agv = p.agg[n * 16 + o];
    float xv = p.x[n * 16 + o];
    float acc = p.bconv[o] + agv;
    #pragma unroll
    for (int i = 0; i < 16; ++i) acc += __shfl(xv, i) * p.Wroot[i * 16 + o];
    float hv = fmaxf(acc, 0.f);
    float hpacc = 0.f;
    #pragma unroll
    for (int i = 0; i < 16; ++i) hpacc += __shfl(hv, i) * p.Wgat[i * 64 + lane];
    p.hpb[(long)n * 64 + lane] = __float2half(hpacc);
    float ss = hpacc * p.a_src[lane];
    float sd = hpacc * p.a_dst[lane];
    #pragma unroll
    for (int off = 32; off; off >>= 1) {
        ss += __shfl_xor(ss, off);
        sd += __shfl_xor(sd, off);
    }
    if (lane == 0) { p.sc_s[n] = ss; p.sc_d[n] = sd; }
}

// ---------------- K3: scatter-GAT; wave per 4 edges, atomic accumulation ----------------
__global__ __launch_bounds__(256) void k_edge(Params p) {
    int gw = (blockIdx.x * blockDim.x + threadIdx.x) >> 6;  // 80000 waves
    int lane = threadIdx.x & 63;
    int e0 = gw * 4;
    if (e0 >= NE) return;
    int srcs[4], dsts[4];
    #pragma unroll
    for (int k = 0; k < 4; ++k) {
        srcs[k] = p.ei[e0 + k];
        dsts[k] = p.ei[NE + e0 + k];
    }
    float w[4];
    #pragma unroll
    for (int k = 0; k < 4; ++k) {
        float sc = p.sc_s[srcs[k]] + p.sc_d[dsts[k]];
        sc = (sc >= 0.f) ? sc : 0.2f * sc;
        w[k] = __expf(sc);
    }
    float hv[4];
    #pragma unroll
    for (int k = 0; k < 4; ++k)
        hv[k] = __half2float(p.hpb[(long)srcs[k] * 64 + lane]);
    #pragma unroll
    for (int k = 0; k < 4; ++k) {
        atomicAdd(&p.gacc[(long)dsts[k] * 64 + lane], w[k] * hv[k]);
        if (lane == 0) atomicAdd(&p.den[dsts[k]], w[k]);
    }
}

// ---------------- K4: fused GAT-normalize + self-loop + mean-pool + MLP head ----------------
__global__ __launch_bounds__(256) void k_head(Params p) {
    int g = blockIdx.x;
    int t = threadIdx.x;
    __shared__ float sd[256];
    __shared__ float pl[64];
    __shared__ float zl[128];
    int r0 = lbound(p.batch, g);
    int r1 = lbound(p.batch, g + 1);
    int o = t & 63, gr = t >> 6;
    float bg = p.bgat[o];
    float part = 0.f;
    for (int r = r0 + gr; r < r1; r += 4) {
        float es = p.sc_s[r] + p.sc_d[r];
        es = (es >= 0.f) ? es : 0.2f * es;
        float l0 = __expf(es);
        float acc = p.gacc[(long)r * 64 + o] + l0 * __half2float(p.hpb[(long)r * 64 + o]);
        float gv = acc / (p.den[r] + l0) + bg;
        part += fmaxf(gv, 0.f);
    }
    sd[t] = part; __syncthreads();
    if (t < 64) {
        float tot = sd[t] + sd[64 + t] + sd[128 + t] + sd[192 + t];
        int cnt = r1 - r0;
        pl[t] = tot / (float)(cnt > 0 ? cnt : 1);
    }
    __syncthreads();
    if (t < 128) {
        float a = p.bfc1[t];
        #pragma unroll 8
        for (int i = 0; i < 64; ++i) a += pl[i] * p.Wfc1[i * 128 + t];
        zl[t] = fmaxf(a, 0.f);
    }
    __syncthreads();
    if (t < 64) {
        float v = zl[t] * p.Wfc2[t] + zl[t + 64] * p.Wfc2[t + 64];
        #pragma unroll
        for (int off = 32; off; off >>= 1) v += __shfl_xor(v, off);
        if (t == 0) p.out[g] = v + p.bfc2[0];
    }
}

extern "C" void kernel_launch(void* const* d_in, const int* in_sizes, int n_in,
                              void* d_out, int out_size, void* d_ws, size_t ws_size,
                              hipStream_t stream) {
    (void)in_sizes; (void)n_in; (void)out_size; (void)ws_size;
    char* w = (char*)d_ws;
    size_t o0 = 0;                             // agg    NN*16 f32   (zeroed)
    size_t o1 = o0 + (size_t)NN * 16 * 4;      // gacc   NN*64 f32   (zeroed)
    size_t o2 = o1 + (size_t)NN * 64 * 4;      // den    NN f32      (zeroed)
    size_t o3 = o2 + (size_t)NN * 4;           // hpb    NN*64 f16
    size_t o4 = o3 + (size_t)NN * 64 * 2;      // sc_s   NN f32
    size_t o5 = o4 + (size_t)NN * 4;           // sc_d   NN f32

    Params P;
    P.x     = (const float*)d_in[0];
    P.ei    = (const int*)d_in[1];
    P.ea    = (const float*)d_in[2];
    P.batch = (const int*)d_in[3];
    P.We    = (const float*)d_in[4];
    P.be    = (const float*)d_in[5];
    P.Wroot = (const float*)d_in[6];
    P.bconv = (const float*)d_in[7];
    P.Wgat  = (const float*)d_in[8];
    P.a_src = (const float*)d_in[9];
    P.a_dst = (const float*)d_in[10];
    P.bgat  = (const float*)d_in[11];
    P.Wfc1  = (const float*)d_in[12];
    P.bfc1  = (const float*)d_in[13];
    P.Wfc2  = (const float*)d_in[14];
    P.bfc2  = (const float*)d_in[15];
    P.out   = (float*)d_out;
    P.agg   = (float*)(w + o0);
    P.gacc  = (float*)(w + o1);
    P.den   = (float*)(w + o2);
    P.hpb   = (__half*)(w + o3);
    P.sc_s  = (float*)(w + o4);
    P.sc_d  = (float*)(w + o5);

    (void)hipMemsetAsync(w, 0, o3, stream);   // agg + gacc + den
    k_msg<<<1250, 256, 0, stream>>>(P);
    k_node<<<(NN + 3) / 4, 256, 0, stream>>>(P);
    k_edge<<<(NE / 4 + 3) / 4, 256, 0, stream>>>(P);
    k_head<<<NG, 256, 0, stream>>>(P);
}